// Round 6
// baseline (253.665 us; speedup 1.0000x reference)
//
#include <hip/hip_runtime.h>
#include <cstdint>
#include <cstddef>

#define N_INST 200
#define HWPIX (448 * 448)        // 200704 pixels per mask
#define W64 3136                 // uint64 words per packed mask
#define W16 12544                // uint16 words per packed mask
#define SIGMA 2.0f
#define NCHUNK 16                // K-split factor in pair kernel
#define NTILE 325                // triangular 8x8 tiles over a 25x25 tile grid

// workspace layout (bytes)
#define P_SLAB  (N_INST * N_INST)              // ints per partial-count slab
#define OFF_P   5017600                        // after packed (200*3136*8)
#define OFF_SP  (OFF_P + NCHUNK * P_SLAB * 4)  // per-chunk per-mask popcounts
#define OFF_DT  (OFF_SP + NCHUNK * 256 * 4)    // DTf[j*200+i] fp32, i<j only
#define OFF_CMP (OFF_DT + N_INST * N_INST * 4) // comp[200] fp32

// ---------------------------------------------------------------------------
// K1: bitpack, fully coalesced. grid (49, 200); block handles 4096 px.
// KEY: popcount/AND are invariant under any fixed pixel permutation applied
// uniformly to all masks, so we choose the bit mapping that makes every load
// instruction lane-contiguous (16 B/lane): thread t packs 4 bits from each of
// float4 slots {s*256+t : s=0..3}. (Round-5 version strided lanes by 64 B per
// instruction -> 64 cache lines/wave/inst, L1-re-hit dependent.)
// word w = bx*256+t, bit 4s+q  <-  pixel bx*4096 + s*1024 + t*4 + q.
// ---------------------------------------------------------------------------
__global__ void pack_kernel(const float* __restrict__ seg,
                            uint16_t* __restrict__ packed16) {
    const int mask = blockIdx.y;
    const int t    = threadIdx.x;
    const float4* s4 = (const float4*)(seg + (size_t)mask * HWPIX
                                           + (size_t)blockIdx.x * 4096);
    uint32_t m = 0;
#pragma unroll
    for (int s = 0; s < 4; ++s) {
        const float4 v = s4[s * 256 + t];          // lane-contiguous 16B/lane
        uint32_t b = 0;
        b |= (v.x > 0.5f) ? 1u : 0u;
        b |= (v.y > 0.5f) ? 2u : 0u;
        b |= (v.z > 0.5f) ? 4u : 0u;
        b |= (v.w > 0.5f) ? 8u : 0u;
        m |= b << (4 * s);
    }
    packed16[(size_t)mask * W16 + blockIdx.x * 256 + t] = (uint16_t)m;
}

// ---------------------------------------------------------------------------
// K2: pairwise intersection counts, 8x8 tile per wave, K-split by NCHUNK=16.
// 325 tiles x 16 chunks = 5200 waves (~5/SIMD latency hiding, vs 2600 in r5).
// Off-diagonal cells -> P[chunk][j][i]; diagonal (i==j) -> SP[chunk][i]
// (per-chunk per-mask popcounts for free, no atomics, no zero-init).
// Wave-sums fit 16 bits (<= 4 iters * 64 bits * 64 lanes = 16384 < 65536):
// counts packed 2-per-int -> 32-reg x 6-step butterfly (exact mod 2^32).
// ---------------------------------------------------------------------------
__global__ void pair_kernel(const uint64_t* __restrict__ packed,
                            int* __restrict__ P,
                            int* __restrict__ SP) {
    const int wt   = blockIdx.x * 4 + (threadIdx.x >> 6);   // 0..5199
    const int lane = threadIdx.x & 63;
    const int t     = wt >> 4;        // tile id 0..324
    const int chunk = wt & 15;

    // decode triangular tile id: t = jt*(jt+1)/2 + it, 0 <= it <= jt <= 24
    int jt = (int)((sqrtf((float)(8 * t + 1)) - 1.0f) * 0.5f);
    while ((jt + 1) * (jt + 2) / 2 <= t) ++jt;
    while (jt * (jt + 1) / 2 > t) --jt;
    const int it = t - jt * (jt + 1) / 2;
    const int i0 = 8 * it, j0 = 8 * jt;

    const int ks = (chunk * 49) >> 4;          // 0,3,6,...,45
    const int ke = ((chunk + 1) * 49) >> 4;    // 3,6,...,45,49

    const uint64_t* A = packed + (size_t)i0 * W64;
    const uint64_t* B = packed + (size_t)j0 * W64;

    int c[64];
#pragma unroll
    for (int x = 0; x < 64; ++x) c[x] = 0;

    for (int kb = ks; kb < ke; ++kb) {
        const int k = kb * 64 + lane;
        uint64_t a[8], b[8];
#pragma unroll
        for (int r = 0; r < 8; ++r) { a[r] = A[k + r * W64]; b[r] = B[k + r * W64]; }
#pragma unroll
        for (int r = 0; r < 8; ++r)
#pragma unroll
            for (int cc = 0; cc < 8; ++cc)
                c[r * 8 + cc] += __popcll(a[r] & b[cc]);
    }

    // pack two counts per int, butterfly-reduce
    int p[32];
#pragma unroll
    for (int m = 0; m < 32; ++m) p[m] = c[2 * m] + (c[2 * m + 1] << 16);
#pragma unroll
    for (int off = 1; off < 64; off <<= 1) {
#pragma unroll
        for (int m = 0; m < 32; ++m) p[m] += __shfl_xor(p[m], off, 64);
    }

    if (lane == 0) {
#pragma unroll
        for (int r = 0; r < 8; ++r) {
#pragma unroll
            for (int cc = 0; cc < 8; ++cc) {
                const int idx = r * 8 + cc;
                const int val = (idx & 1) ? (int)(((unsigned)p[idx >> 1]) >> 16)
                                          : (p[idx >> 1] & 0xFFFF);
                const int i = i0 + r, j = j0 + cc;
                if (i < j)       P[chunk * P_SLAB + j * N_INST + i] = val;
                else if (i == j) SP[chunk * 256 + i] = val;   // popc(a&a)=|mask|
            }
        }
    }
}

// ---------------------------------------------------------------------------
// K3: reduce chunk partials -> DTf[j*200+i] = decay_iou[i][j] (i<j), AND fuse
// comp[j] = max_{i<j} DTf[j][i] — it's exactly the row this block computes.
// ---------------------------------------------------------------------------
__global__ void iou_comp_kernel(const int* __restrict__ P,
                                const int* __restrict__ SP,
                                const int* __restrict__ labels,
                                float* __restrict__ DTf,
                                float* __restrict__ comp) {
    const int j = blockIdx.x;
    const int t = threadIdx.x;
    int sj = 0;
#pragma unroll
    for (int cch = 0; cch < NCHUNK; ++cch) sj += SP[cch * 256 + j];
    const int lj = labels[j];
    float m = 0.0f;                            // j=0: empty column -> comp 0
    for (int i = t; i < j; i += 64) {
        int inter = 0;
#pragma unroll
        for (int cch = 0; cch < NCHUNK; ++cch)
            inter += P[cch * P_SLAB + j * N_INST + i];
        int si = 0;
#pragma unroll
        for (int cch = 0; cch < NCHUNK; ++cch) si += SP[cch * 256 + i];
        const float iou = (float)inter / (float)(si + sj - inter);
        const float d = (labels[i] == lj) ? iou : 0.0f;
        DTf[j * N_INST + i] = d;
        m = fmaxf(m, d);
    }
#pragma unroll
    for (int off = 1; off < 64; off <<= 1) m = fmaxf(m, __shfl_xor(m, off, 64));
    if (t == 0) comp[j] = m;
}

// ---------------------------------------------------------------------------
// K4: out[j] = scores[j] * exp(SIGMA * min_i(comp[i]^2 - d_ij^2)),
//     d_ij = decay_iou[i][j] = (i<j ? DTf[j*200+i] : 0).
// (min of exp == exp of min; exp monotone.) Coalesced row reads, L2-hot.
// ---------------------------------------------------------------------------
__global__ void finalize_kernel(const float* __restrict__ DTf,
                                const float* __restrict__ comp,
                                const float* __restrict__ scores,
                                float* __restrict__ out) {
    const int j = blockIdx.x;
    const int t = threadIdx.x;
    const float* row = DTf + (size_t)j * N_INST;
    float mn = 3.4e38f;
    for (int i = t; i < N_INST; i += 64) {
        const float ci = comp[i];
        float v = ci * ci;
        if (i < j) { const float d = row[i]; v -= d * d; }
        mn = fminf(mn, v);
    }
#pragma unroll
    for (int off = 1; off < 64; off <<= 1) mn = fminf(mn, __shfl_xor(mn, off, 64));
    if (t == 0) out[j] = scores[j] * expf(SIGMA * mn);
}

extern "C" void kernel_launch(void* const* d_in, const int* in_sizes, int n_in,
                              void* d_out, int out_size, void* d_ws, size_t ws_size,
                              hipStream_t stream) {
    const float* seg    = (const float*)d_in[0];   // (200,448,448) fp32 binary
    const float* scores = (const float*)d_in[1];   // (200,) fp32
    const int*   labels = (const int*)d_in[2];     // (200,) int32
    float* out = (float*)d_out;                    // (200,) fp32

    uint64_t* packed   = (uint64_t*)d_ws;
    uint16_t* packed16 = (uint16_t*)d_ws;
    int*      P        = (int*)((char*)d_ws + OFF_P);
    int*      SP       = (int*)((char*)d_ws + OFF_SP);
    float*    DTf      = (float*)((char*)d_ws + OFF_DT);
    float*    comp     = (float*)((char*)d_ws + OFF_CMP);

    {
        dim3 grid(49, N_INST);
        pack_kernel<<<grid, 256, 0, stream>>>(seg, packed16);
    }
    pair_kernel<<<NTILE * NCHUNK / 4, 256, 0, stream>>>(packed, P, SP);
    iou_comp_kernel<<<N_INST, 64, 0, stream>>>(P, SP, labels, DTf, comp);
    finalize_kernel<<<N_INST, 64, 0, stream>>>(DTf, comp, scores, out);
}